// Round 2
// baseline (3044.202 us; speedup 1.0000x reference)
//
#include <hip/hip_runtime.h>
#include <math.h>

// Problem constants (fixed by setup_inputs: B=4, D=128, T=8, P=4096)
#define BB 4
#define DD 128
#define TT 8
#define PP 4096
#define KK 10
#define NT 7              // T-1 frame pairs
#define BP (BB*PP)        // 16384 points per frame across batch
#define NQ (NT*BP)        // 114688 total queries
#define NBLK_COS 896
#define QPB 128           // queries per block in cos kernel (NBLK_COS*QPB == NQ)

#define CHUNKS 4
#define CSZ (PP/CHUNKS)   // 1024 candidates per chunk (16 KB LDS)

// Workspace layout (bytes, all 256-aligned)
// The KNN partial lists (36.7 MB) alias the featT region: they are produced
// and fully consumed (knn_partial -> knn_merge) BEFORE transpose_kernel
// writes featT. Same-stream ordering makes this safe.
#define OFF_FEATT 0u                 // NQ*DD floats  = 58,720,256 B
#define OFF_IDX   58720256u          // NQ*KK ints    =  4,587,520 B
#define OFF_DV    63307776u          // NQ floats     =    458,752 B
#define OFF_NORM  63766528u          // NQ floats     =    458,752 B
#define OFF_SCALE 64225280u          // NT floats (padded to 256)
#define OFF_PART  64225536u          // NBLK_COS floats

// ---------------------------------------------------------------------------
// Kernel A1: chunked exact top-10 partial lists.
// Grid (16*CHUNKS, BB, NT); block 256. Each block stages one 1024-candidate
// chunk in 16 KB LDS and scans it for 256 queries (thread per query).
// Distance formula is byte-identical to the round-1 kernel, so the selected
// sets match jax.lax.top_k exactly (strict '>' + ascending-index scan).
// ---------------------------------------------------------------------------
__global__ __launch_bounds__(256) void knn_partial_kernel(
    const float* __restrict__ pts4, int2* __restrict__ part) {
  __shared__ float4 cand[CSZ];  // 16 KB
  const int qg = blockIdx.x >> 2;      // query group 0..15
  const int c = blockIdx.x & 3;        // chunk 0..3
  const int b = blockIdx.y, t = blockIdx.z;
  const float4* src0 = (const float4*)pts4 + ((size_t)(b * TT + t) * PP);
  const int jbase = c * CSZ;

  for (int i = threadIdx.x; i < CSZ; i += 256) {
    float4 v = src0[jbase + i];
    v.w = fmaf(v.x, v.x, fmaf(v.y, v.y, v.z * v.z));
    cand[i] = v;
  }
  __syncthreads();

  const int p = qg * 256 + threadIdx.x;
  float4 q = src0[p];
  q.w = fmaf(q.x, q.x, fmaf(q.y, q.y, q.z * q.z));

  float bv[KK];
  int bi[KK];
#pragma unroll
  for (int i = 0; i < KK; ++i) { bv[i] = -INFINITY; bi[i] = 0; }

#define DIST(cc) (2.0f * fmaf(q.x, cc.x, fmaf(q.y, cc.y, q.z * cc.z)) - q.w - cc.w)
#define INS(ndv, jj)                                                   \
  if ((ndv) > bv[KK - 1]) {                                            \
    bv[KK - 1] = (ndv); bi[KK - 1] = (jj);                             \
    _Pragma("unroll") for (int i = KK - 1; i > 0; --i) {               \
      bool sw = bv[i] > bv[i - 1];                                     \
      float tv = sw ? bv[i - 1] : bv[i];                               \
      bv[i - 1] = sw ? bv[i] : bv[i - 1]; bv[i] = tv;                  \
      int ti = sw ? bi[i - 1] : bi[i];                                 \
      bi[i - 1] = sw ? bi[i] : bi[i - 1]; bi[i] = ti;                  \
    }                                                                  \
  }

  for (int j = 0; j < CSZ; j += 4) {
    float4 c0 = cand[j], c1 = cand[j + 1], c2 = cand[j + 2], c3 = cand[j + 3];
    float nd0 = DIST(c0), nd1 = DIST(c1), nd2 = DIST(c2), nd3 = DIST(c3);
    INS(nd0, jbase + j);
    INS(nd1, jbase + j + 1);
    INS(nd2, jbase + j + 2);
    INS(nd3, jbase + j + 3);
  }
#undef DIST
#undef INS

  // Layout [c][r][qid] so both the write here and the merge read coalesce.
  const size_t qid = (size_t)(t * BB + b) * PP + p;
#pragma unroll
  for (int r = 0; r < KK; ++r)
    part[(size_t)(c * KK + r) * NQ + qid] = make_int2(__float_as_int(bv[r]), bi[r]);
}

// ---------------------------------------------------------------------------
// Kernel A2: merge 4 partial top-10 lists -> exact global top-10, + disp var.
// Comparator (value desc, index asc) reproduces jax.lax.top_k tie-breaking
// exactly, independent of merge scan order.
// ---------------------------------------------------------------------------
__global__ __launch_bounds__(256) void knn_merge_kernel(
    const float* __restrict__ pts4, const int2* __restrict__ part,
    int* __restrict__ idx_out, float* __restrict__ dv_out) {
  const int g = blockIdx.x * 256 + threadIdx.x;  // query id 0..NQ-1
  const int t = g >> 14;                         // / BP
  const int rem = g & (BP - 1);
  const int b = rem >> 12;                       // / PP
  const int p = rem & (PP - 1);

  float bv[KK];
  int bi[KK];
#pragma unroll
  for (int i = 0; i < KK; ++i) { bv[i] = -INFINITY; bi[i] = 0x7FFFFFFF; }

#pragma unroll
  for (int c = 0; c < CHUNKS; ++c) {
#pragma unroll
    for (int r = 0; r < KK; ++r) {
      int2 e = part[(size_t)(c * KK + r) * NQ + g];
      float v = __int_as_float(e.x);
      int j = e.y;
      if (v > bv[KK - 1] || (v == bv[KK - 1] && j < bi[KK - 1])) {
        bv[KK - 1] = v; bi[KK - 1] = j;
#pragma unroll
        for (int i = KK - 1; i > 0; --i) {
          bool sw = (bv[i] > bv[i - 1]) || (bv[i] == bv[i - 1] && bi[i] < bi[i - 1]);
          float tv = sw ? bv[i - 1] : bv[i];
          bv[i - 1] = sw ? bv[i] : bv[i - 1]; bv[i] = tv;
          int ti = sw ? bi[i - 1] : bi[i];
          bi[i - 1] = sw ? bi[i] : bi[i - 1]; bi[i] = ti;
        }
      }
    }
  }

  const float4* src0 = (const float4*)pts4 + ((size_t)(b * TT + t) * PP);
  const float4* src1 = src0 + PP;  // frame t+1
  float4 a0 = src0[p], a1 = src1[p];
  const float dqx = a1.x - a0.x, dqy = a1.y - a0.y, dqz = a1.z - a0.z;
  float s = 0.0f;
#pragma unroll
  for (int k = 0; k < KK; ++k) {
    int j = bi[k];
    float4 c0 = src0[j], c1 = src1[j];
    float dx = (c1.x - c0.x) - dqx;
    float dy = (c1.y - c0.y) - dqy;
    float dz = (c1.z - c0.z) - dqz;
    s += fmaf(dx, dx, fmaf(dy, dy, dz * dz));
  }

  dv_out[g] = s * (1.0f / KK);
#pragma unroll
  for (int k = 0; k < KK; ++k) idx_out[(size_t)g * KK + k] = bi[k];
}

// ---------------------------------------------------------------------------
// Kernel B: transpose encoded[b][d][t*P+p] -> featT[t][b][p][d]  (t < NT)
// ---------------------------------------------------------------------------
__global__ __launch_bounds__(256) void transpose_kernel(
    const float* __restrict__ encoded, float* __restrict__ featT) {
  __shared__ float tile[32][33];
  const int slice = blockIdx.z;  // t*BB + b
  const int t = slice / BB, b = slice % BB;
  const int p0 = blockIdx.x * 32, d0 = blockIdx.y * 32;
  const int tx = threadIdx.x, ty = threadIdx.y;
#pragma unroll
  for (int r = 0; r < 4; ++r) {
    int d = d0 + ty + r * 8;
    tile[ty + r * 8][tx] =
        encoded[((size_t)(b * DD + d)) * (TT * PP) + (size_t)t * PP + p0 + tx];
  }
  __syncthreads();
#pragma unroll
  for (int r = 0; r < 4; ++r) {
    int p = p0 + ty + r * 8;
    featT[((size_t)slice * PP + p) * DD + d0 + tx] = tile[tx][ty + r * 8];
  }
}

// ---------------------------------------------------------------------------
// Kernel N: per-point feature L2 norms (wave per point)
// ---------------------------------------------------------------------------
__global__ __launch_bounds__(256) void norms_kernel(
    const float* __restrict__ featT, float* __restrict__ norms) {
  const int w = threadIdx.x >> 6, lane = threadIdx.x & 63;
  const int wid = blockIdx.x * 4 + w;
  for (int i = 0; i < 32; ++i) {
    const int g = wid * 32 + i;
    float2 f = *(const float2*)(featT + (size_t)g * DD + lane * 2);
    float part = fmaf(f.x, f.x, f.y * f.y);
#pragma unroll
    for (int o = 32; o > 0; o >>= 1) part += __shfl_xor(part, o);
    if (lane == 0) norms[g] = sqrtf(part);
  }
}

// ---------------------------------------------------------------------------
// Kernel C: exact lower-median per t via 4-pass radix select on float bits
// ---------------------------------------------------------------------------
__global__ __launch_bounds__(256) void median_kernel(
    const float* __restrict__ disp_var, float* __restrict__ scale) {
  const int t = blockIdx.x;
  const unsigned* u = (const unsigned*)(disp_var + (size_t)t * BP);
  __shared__ unsigned hist[256];
  __shared__ unsigned sh_prefix;
  __shared__ int sh_rank;
  if (threadIdx.x == 0) { sh_prefix = 0u; sh_rank = (BP - 1) >> 1; }
  __syncthreads();
  for (int pass = 0; pass < 4; ++pass) {
    const int shift = 24 - pass * 8;
    hist[threadIdx.x] = 0u;
    __syncthreads();
    const unsigned hmask = (pass == 0) ? 0u : (0xFFFFFFFFu << (shift + 8));
    const unsigned prefix = sh_prefix;
    for (int i = threadIdx.x; i < BP; i += 256) {
      unsigned v = u[i];
      if ((v & hmask) == prefix) atomicAdd(&hist[(v >> shift) & 255u], 1u);
    }
    __syncthreads();
    if (threadIdx.x == 0) {
      int rank = sh_rank;
      unsigned run = 0u;
      for (int c = 0; c < 256; ++c) {
        unsigned h = hist[c];
        if (run + h > (unsigned)rank) {
          sh_rank = rank - (int)run;
          sh_prefix = prefix | ((unsigned)c << shift);
          break;
        }
        run += h;
      }
    }
    __syncthreads();
  }
  if (threadIdx.x == 0) {
    float med = __uint_as_float(sh_prefix);
    scale[t] = fmaxf(med, 1e-6f);
  }
}

// ---------------------------------------------------------------------------
// Kernel D: cosine similarity + rigidity loss, deterministic block partials
// ---------------------------------------------------------------------------
__global__ __launch_bounds__(256) void cos_loss_kernel(
    const float* __restrict__ featT, const int* __restrict__ idxw,
    const float* __restrict__ norms, const float* __restrict__ dv,
    const float* __restrict__ scale, float* __restrict__ partial) {
  const int w = threadIdx.x >> 6, lane = threadIdx.x & 63;
  __shared__ float wsum[4];
  float acc = 0.0f;
  const int qbase = blockIdx.x * QPB + w * (QPB / 4);
  for (int i = 0; i < QPB / 4; ++i) {
    const int g = qbase + i;
    const int t = g >> 14;
    const int p = g & (PP - 1);
    const int slice = g - p;        // base of this (t,b) slice
    const float* fbase = featT + (size_t)g * DD;
    float2 fq = *(const float2*)(fbase + lane * 2);
    float nq = fmaxf(norms[g], 1e-8f);
    const int* ip = idxw + (size_t)g * KK;
    float msum = 0.0f;
#pragma unroll
    for (int k = 0; k < KK; ++k) {
      int j = ip[k];
      const float* nb = featT + (size_t)(slice + j) * DD;
      float2 fn = *(const float2*)(nb + lane * 2);
      float part = fmaf(fq.x, fn.x, fq.y * fn.y);
#pragma unroll
      for (int o = 32; o > 0; o >>= 1) part += __shfl_xor(part, o);
      float nn = fmaxf(norms[slice + j], 1e-8f);
      msum += part / (nq * nn);
    }
    float mean_sim = msum * (1.0f / KK);
    float rig = expf(-dv[g] / scale[t]);
    acc += rig * (1.0f - mean_sim);
  }
  if (lane == 0) wsum[w] = acc;
  __syncthreads();
  if (threadIdx.x == 0)
    partial[blockIdx.x] = (wsum[0] + wsum[1]) + (wsum[2] + wsum[3]);
}

// ---------------------------------------------------------------------------
// Kernel E: final deterministic reduce -> scalar loss
// ---------------------------------------------------------------------------
__global__ __launch_bounds__(256) void final_reduce_kernel(
    const float* __restrict__ partial, float* __restrict__ out) {
  __shared__ float sh[256];
  float s = 0.0f;
  for (int i = threadIdx.x; i < NBLK_COS; i += 256) s += partial[i];
  sh[threadIdx.x] = s;
  __syncthreads();
  for (int st = 128; st > 0; st >>= 1) {
    if (threadIdx.x < st) sh[threadIdx.x] += sh[threadIdx.x + st];
    __syncthreads();
  }
  if (threadIdx.x == 0) out[0] = sh[0] * (1.0f / (float)NQ);
}

extern "C" void kernel_launch(void* const* d_in, const int* in_sizes, int n_in,
                              void* d_out, int out_size, void* d_ws,
                              size_t ws_size, hipStream_t stream) {
  const float* encoded = (const float*)d_in[0];
  const float* pts4 = (const float*)d_in[1];
  char* ws = (char*)d_ws;
  float* featT = (float*)(ws + OFF_FEATT);
  int2* partk = (int2*)(ws + OFF_FEATT);  // aliases featT (consumed first)
  int* idxw = (int*)(ws + OFF_IDX);
  float* dv = (float*)(ws + OFF_DV);
  float* norms = (float*)(ws + OFF_NORM);
  float* scale = (float*)(ws + OFF_SCALE);
  float* partial = (float*)(ws + OFF_PART);
  float* outp = (float*)d_out;

  knn_partial_kernel<<<dim3(16 * CHUNKS, BB, NT), 256, 0, stream>>>(pts4, partk);
  knn_merge_kernel<<<NQ / 256, 256, 0, stream>>>(pts4, partk, idxw, dv);
  transpose_kernel<<<dim3(PP / 32, DD / 32, NT * BB), dim3(32, 8), 0, stream>>>(
      encoded, featT);
  norms_kernel<<<NBLK_COS, 256, 0, stream>>>(featT, norms);
  median_kernel<<<NT, 256, 0, stream>>>(dv, scale);
  cos_loss_kernel<<<NBLK_COS, 256, 0, stream>>>(featT, idxw, norms, dv, scale,
                                                partial);
  final_reduce_kernel<<<1, 256, 0, stream>>>(partial, outp);
}

// Round 3
// 1019.045 us; speedup vs baseline: 2.9873x; 2.9873x over previous
//
#include <hip/hip_runtime.h>
#include <math.h>

// Problem constants (fixed by setup_inputs: B=4, D=128, T=8, P=4096)
#define BB 4
#define DD 128
#define TT 8
#define PP 4096
#define KK 10
#define NT 7              // T-1 frame pairs
#define BP (BB*PP)        // 16384 points per frame across batch
#define NQ (NT*BP)        // 114688 total queries
#define NBLK_COS 896
#define QPB 128           // queries per block in cos kernel (NBLK_COS*QPB == NQ)

#define CHUNKS 4
#define CSZ (PP/CHUNKS)   // 1024 candidates per chunk (16 KB LDS)

// Workspace layout (bytes, all 256-aligned)
// part_val (18.3 MB) aliases the featT region: fully consumed by knn_collect
// BEFORE transpose_kernel writes featT (same-stream ordering).
#define OFF_FEATT 0u                 // NQ*DD floats  = 58,720,256 B
#define OFF_IDX   58720256u          // NQ*KK ints    =  4,587,520 B
#define OFF_DV    63307776u          // NQ floats     =    458,752 B
#define OFF_NORM  63766528u          // NQ floats     =    458,752 B
#define OFF_SCALE 64225280u          // NT floats (padded to 256)
#define OFF_PART  64225536u          // NBLK_COS floats

// Shared distance expression — MUST be textually identical in A1 and B so nd
// values are bit-identical (thr equality tests depend on it).
__device__ __forceinline__ float neg_dist(const float4 q, const float4 c) {
  float inner = fmaf(q.x, c.x, fmaf(q.y, c.y, q.z * c.z));
  return 2.0f * inner - q.w - c.w;
}

// Branchless values-only top-10 insert: replace current min (bv[9]) if larger,
// one bubble pass restores descending order. 19 VALU, zero divergence.
__device__ __forceinline__ void ins_val(float (&bv)[KK], float nd) {
  bv[KK - 1] = fmaxf(bv[KK - 1], nd);
#pragma unroll
  for (int i = KK - 1; i > 0; --i) {
    float hi = fmaxf(bv[i - 1], bv[i]);
    float lo = fminf(bv[i - 1], bv[i]);
    bv[i - 1] = hi;
    bv[i] = lo;
  }
}

// ---------------------------------------------------------------------------
// Kernel A1: per-chunk top-10 neg-dist VALUES (no indices).
// Grid (16*CHUNKS, BB, NT) = 1792 blocks -> ~28 waves/CU occupancy.
// ---------------------------------------------------------------------------
__global__ __launch_bounds__(256) void knn_thr_partial(
    const float* __restrict__ pts4, float* __restrict__ part) {
  __shared__ float4 cand[CSZ];  // 16 KB
  const int qg = blockIdx.x >> 2;      // query group 0..15
  const int c = blockIdx.x & 3;        // chunk 0..3
  const int b = blockIdx.y, t = blockIdx.z;
  const float4* src0 = (const float4*)pts4 + ((size_t)(b * TT + t) * PP);
  const int jbase = c * CSZ;

  for (int i = threadIdx.x; i < CSZ; i += 256) {
    float4 v = src0[jbase + i];
    v.w = fmaf(v.x, v.x, fmaf(v.y, v.y, v.z * v.z));
    cand[i] = v;
  }
  __syncthreads();

  const int p = qg * 256 + threadIdx.x;
  float4 q = src0[p];
  q.w = fmaf(q.x, q.x, fmaf(q.y, q.y, q.z * q.z));

  float bv[KK];
#pragma unroll
  for (int i = 0; i < KK; ++i) bv[i] = -INFINITY;

  for (int j = 0; j < CSZ; j += 4) {
    float4 c0 = cand[j], c1 = cand[j + 1], c2 = cand[j + 2], c3 = cand[j + 3];
    float nd0 = neg_dist(q, c0);
    float nd1 = neg_dist(q, c1);
    float nd2 = neg_dist(q, c2);
    float nd3 = neg_dist(q, c3);
    ins_val(bv, nd0);
    ins_val(bv, nd1);
    ins_val(bv, nd2);
    ins_val(bv, nd3);
  }

  const size_t qid = (size_t)(t * BB + b) * PP + p;
#pragma unroll
  for (int r = 0; r < KK; ++r)
    part[(size_t)(c * KK + r) * NQ + qid] = bv[r];
}

// ---------------------------------------------------------------------------
// Kernel B: merge partial values -> exact 10th-largest thr, then full rescan:
// strict nd>thr -> emit index + disp contribution; nd==thr ties collected in
// ascending index order, first (10 - strict) taken. Exactly top_k's set.
// ---------------------------------------------------------------------------
__global__ __launch_bounds__(256) void knn_collect(
    const float* __restrict__ pts4, const float* __restrict__ part,
    int* __restrict__ idx_out, float* __restrict__ dv_out) {
  __shared__ float4 cand[PP];  // 64 KB
  const int qg = blockIdx.x;
  const int b = blockIdx.y, t = blockIdx.z;
  const float4* src0 = (const float4*)pts4 + ((size_t)(b * TT + t) * PP);
  const float4* src1 = src0 + PP;  // frame t+1

  for (int i = threadIdx.x; i < PP; i += 256) {
    float4 v = src0[i];
    v.w = fmaf(v.x, v.x, fmaf(v.y, v.y, v.z * v.z));
    cand[i] = v;
  }
  __syncthreads();

  const int p = qg * 256 + threadIdx.x;
  const size_t g = (size_t)(t * BB + b) * PP + p;

  // ---- exact 10th-largest value over all 4096 (tournament of chunk top-10s)
  float bv[KK];
#pragma unroll
  for (int i = 0; i < KK; ++i) bv[i] = -INFINITY;
#pragma unroll
  for (int c = 0; c < CHUNKS; ++c) {
#pragma unroll
    for (int r = 0; r < KK; ++r) ins_val(bv, part[(size_t)(c * KK + r) * NQ + g]);
  }
  const float thr = bv[KK - 1];

  float4 q = cand[p];  // has xx in .w
  float4 a1 = src1[p];
  const float dqx = a1.x - q.x, dqy = a1.y - q.y, dqz = a1.z - q.z;

  int cnt = 0, tcnt = 0;
  int tie[KK];
#pragma unroll
  for (int r = 0; r < KK; ++r) tie[r] = 0;
  float s = 0.0f;
  int* myidx = idx_out + g * KK;

  for (int j = 0; j < PP; j += 4) {
#pragma unroll
    for (int u = 0; u < 4; ++u) {
      float4 cc = cand[j + u];
      float nd = neg_dist(q, cc);
      if (nd > thr) {
        myidx[cnt] = j + u;
        ++cnt;
        float4 n1 = src1[j + u];
        float dx = (n1.x - cc.x) - dqx;
        float dy = (n1.y - cc.y) - dqy;
        float dz = (n1.z - cc.z) - dqz;
        s += fmaf(dx, dx, fmaf(dy, dy, dz * dz));
      } else if (nd == thr) {
#pragma unroll
        for (int r = 0; r < KK; ++r) tie[r] = (tcnt == r) ? (j + u) : tie[r];
        ++tcnt;
      }
    }
  }

  const int need = KK - cnt;  // >= 1; take first `need` ties (ascending index)
#pragma unroll
  for (int r = 0; r < KK; ++r) {
    if (r < need) {
      int j = tie[r];
      float4 cc = cand[j];
      float4 n1 = src1[j];
      float dx = (n1.x - cc.x) - dqx;
      float dy = (n1.y - cc.y) - dqy;
      float dz = (n1.z - cc.z) - dqz;
      s += fmaf(dx, dx, fmaf(dy, dy, dz * dz));
      myidx[cnt + r] = j;
    }
  }

  dv_out[g] = s * (1.0f / KK);
}

// ---------------------------------------------------------------------------
// Kernel B2: transpose encoded[b][d][t*P+p] -> featT[t][b][p][d]  (t < NT)
// ---------------------------------------------------------------------------
__global__ __launch_bounds__(256) void transpose_kernel(
    const float* __restrict__ encoded, float* __restrict__ featT) {
  __shared__ float tile[32][33];
  const int slice = blockIdx.z;  // t*BB + b
  const int t = slice / BB, b = slice % BB;
  const int p0 = blockIdx.x * 32, d0 = blockIdx.y * 32;
  const int tx = threadIdx.x, ty = threadIdx.y;
#pragma unroll
  for (int r = 0; r < 4; ++r) {
    int d = d0 + ty + r * 8;
    tile[ty + r * 8][tx] =
        encoded[((size_t)(b * DD + d)) * (TT * PP) + (size_t)t * PP + p0 + tx];
  }
  __syncthreads();
#pragma unroll
  for (int r = 0; r < 4; ++r) {
    int p = p0 + ty + r * 8;
    featT[((size_t)slice * PP + p) * DD + d0 + tx] = tile[tx][ty + r * 8];
  }
}

// ---------------------------------------------------------------------------
// Kernel N: per-point feature L2 norms (wave per point)
// ---------------------------------------------------------------------------
__global__ __launch_bounds__(256) void norms_kernel(
    const float* __restrict__ featT, float* __restrict__ norms) {
  const int w = threadIdx.x >> 6, lane = threadIdx.x & 63;
  const int wid = blockIdx.x * 4 + w;
  for (int i = 0; i < 32; ++i) {
    const int g = wid * 32 + i;
    float2 f = *(const float2*)(featT + (size_t)g * DD + lane * 2);
    float part = fmaf(f.x, f.x, f.y * f.y);
#pragma unroll
    for (int o = 32; o > 0; o >>= 1) part += __shfl_xor(part, o);
    if (lane == 0) norms[g] = sqrtf(part);
  }
}

// ---------------------------------------------------------------------------
// Kernel C: exact lower-median per t via 4-pass radix select on float bits
// ---------------------------------------------------------------------------
__global__ __launch_bounds__(256) void median_kernel(
    const float* __restrict__ disp_var, float* __restrict__ scale) {
  const int t = blockIdx.x;
  const unsigned* u = (const unsigned*)(disp_var + (size_t)t * BP);
  __shared__ unsigned hist[256];
  __shared__ unsigned sh_prefix;
  __shared__ int sh_rank;
  if (threadIdx.x == 0) { sh_prefix = 0u; sh_rank = (BP - 1) >> 1; }
  __syncthreads();
  for (int pass = 0; pass < 4; ++pass) {
    const int shift = 24 - pass * 8;
    hist[threadIdx.x] = 0u;
    __syncthreads();
    const unsigned hmask = (pass == 0) ? 0u : (0xFFFFFFFFu << (shift + 8));
    const unsigned prefix = sh_prefix;
    for (int i = threadIdx.x; i < BP; i += 256) {
      unsigned v = u[i];
      if ((v & hmask) == prefix) atomicAdd(&hist[(v >> shift) & 255u], 1u);
    }
    __syncthreads();
    if (threadIdx.x == 0) {
      int rank = sh_rank;
      unsigned run = 0u;
      for (int c = 0; c < 256; ++c) {
        unsigned h = hist[c];
        if (run + h > (unsigned)rank) {
          sh_rank = rank - (int)run;
          sh_prefix = prefix | ((unsigned)c << shift);
          break;
        }
        run += h;
      }
    }
    __syncthreads();
  }
  if (threadIdx.x == 0) {
    float med = __uint_as_float(sh_prefix);
    scale[t] = fmaxf(med, 1e-6f);
  }
}

// ---------------------------------------------------------------------------
// Kernel D: cosine similarity + rigidity loss, deterministic block partials
// ---------------------------------------------------------------------------
__global__ __launch_bounds__(256) void cos_loss_kernel(
    const float* __restrict__ featT, const int* __restrict__ idxw,
    const float* __restrict__ norms, const float* __restrict__ dv,
    const float* __restrict__ scale, float* __restrict__ partial) {
  const int w = threadIdx.x >> 6, lane = threadIdx.x & 63;
  __shared__ float wsum[4];
  float acc = 0.0f;
  const int qbase = blockIdx.x * QPB + w * (QPB / 4);
  for (int i = 0; i < QPB / 4; ++i) {
    const int g = qbase + i;
    const int t = g >> 14;
    const int p = g & (PP - 1);
    const int slice = g - p;        // base of this (t,b) slice
    const float* fbase = featT + (size_t)g * DD;
    float2 fq = *(const float2*)(fbase + lane * 2);
    float nq = fmaxf(norms[g], 1e-8f);
    const int* ip = idxw + (size_t)g * KK;
    float msum = 0.0f;
#pragma unroll
    for (int k = 0; k < KK; ++k) {
      int j = ip[k];
      const float* nb = featT + (size_t)(slice + j) * DD;
      float2 fn = *(const float2*)(nb + lane * 2);
      float part = fmaf(fq.x, fn.x, fq.y * fn.y);
#pragma unroll
      for (int o = 32; o > 0; o >>= 1) part += __shfl_xor(part, o);
      float nn = fmaxf(norms[slice + j], 1e-8f);
      msum += part / (nq * nn);
    }
    float mean_sim = msum * (1.0f / KK);
    float rig = expf(-dv[g] / scale[t]);
    acc += rig * (1.0f - mean_sim);
  }
  if (lane == 0) wsum[w] = acc;
  __syncthreads();
  if (threadIdx.x == 0)
    partial[blockIdx.x] = (wsum[0] + wsum[1]) + (wsum[2] + wsum[3]);
}

// ---------------------------------------------------------------------------
// Kernel E: final deterministic reduce -> scalar loss
// ---------------------------------------------------------------------------
__global__ __launch_bounds__(256) void final_reduce_kernel(
    const float* __restrict__ partial, float* __restrict__ out) {
  __shared__ float sh[256];
  float s = 0.0f;
  for (int i = threadIdx.x; i < NBLK_COS; i += 256) s += partial[i];
  sh[threadIdx.x] = s;
  __syncthreads();
  for (int st = 128; st > 0; st >>= 1) {
    if (threadIdx.x < st) sh[threadIdx.x] += sh[threadIdx.x + st];
    __syncthreads();
  }
  if (threadIdx.x == 0) out[0] = sh[0] * (1.0f / (float)NQ);
}

extern "C" void kernel_launch(void* const* d_in, const int* in_sizes, int n_in,
                              void* d_out, int out_size, void* d_ws,
                              size_t ws_size, hipStream_t stream) {
  const float* encoded = (const float*)d_in[0];
  const float* pts4 = (const float*)d_in[1];
  char* ws = (char*)d_ws;
  float* featT = (float*)(ws + OFF_FEATT);
  float* part = (float*)(ws + OFF_FEATT);  // aliases featT (consumed first)
  int* idxw = (int*)(ws + OFF_IDX);
  float* dv = (float*)(ws + OFF_DV);
  float* norms = (float*)(ws + OFF_NORM);
  float* scale = (float*)(ws + OFF_SCALE);
  float* partial = (float*)(ws + OFF_PART);
  float* outp = (float*)d_out;

  knn_thr_partial<<<dim3(16 * CHUNKS, BB, NT), 256, 0, stream>>>(pts4, part);
  knn_collect<<<dim3(16, BB, NT), 256, 0, stream>>>(pts4, part, idxw, dv);
  transpose_kernel<<<dim3(PP / 32, DD / 32, NT * BB), dim3(32, 8), 0, stream>>>(
      encoded, featT);
  norms_kernel<<<NBLK_COS, 256, 0, stream>>>(featT, norms);
  median_kernel<<<NT, 256, 0, stream>>>(dv, scale);
  cos_loss_kernel<<<NBLK_COS, 256, 0, stream>>>(featT, idxw, norms, dv, scale,
                                                partial);
  final_reduce_kernel<<<1, 256, 0, stream>>>(partial, outp);
}

// Round 4
// 778.446 us; speedup vs baseline: 3.9106x; 1.3091x over previous
//
#include <hip/hip_runtime.h>
#include <math.h>

// Problem constants (fixed by setup_inputs: B=4, D=128, T=8, P=4096)
#define BB 4
#define DD 128
#define TT 8
#define PP 4096
#define KK 10
#define NT 7              // T-1 frame pairs
#define BP (BB*PP)        // 16384 points per frame across batch
#define NQ (NT*BP)        // 114688 total queries
#define NBLK_COS 896
#define QPB 128           // queries per block in cos kernel (NBLK_COS*QPB == NQ)

#define CHUNKS 4
#define CSZ (PP/CHUNKS)   // 1024 candidates per chunk (16 KB LDS)
#define TCAP 8            // tie-slot cap (>=3-way bitwise ties ~impossible)

// Workspace layout (bytes, all 256-aligned)
// part_val (18.3 MB) aliases the featT region: fully consumed by knn_collect
// BEFORE transpose_kernel writes featT (same-stream ordering).
#define OFF_FEATT 0u                 // NQ*DD floats  = 58,720,256 B
#define OFF_IDX   58720256u          // NQ*KK ints    =  4,587,520 B
#define OFF_DV    63307776u          // NQ floats     =    458,752 B
#define OFF_NORM  63766528u          // NQ floats     =    458,752 B
#define OFF_SCALE 64225280u          // NT floats (padded to 256)
#define OFF_PART  64225536u          // NBLK_COS floats

// Shared distance expression — MUST be textually identical in A1 and B so nd
// values are bit-identical (thr equality tests depend on it).
__device__ __forceinline__ float neg_dist(const float4 q, const float4 c) {
  float inner = fmaf(q.x, c.x, fmaf(q.y, c.y, q.z * c.z));
  return 2.0f * inner - q.w - c.w;
}

// Branchless values-only top-10 insert: replace current min (bv[9]) if larger,
// one bubble pass restores descending order. 19 VALU, zero divergence.
__device__ __forceinline__ void ins_val(float (&bv)[KK], float nd) {
  bv[KK - 1] = fmaxf(bv[KK - 1], nd);
#pragma unroll
  for (int i = KK - 1; i > 0; --i) {
    float hi = fmaxf(bv[i - 1], bv[i]);
    float lo = fminf(bv[i - 1], bv[i]);
    bv[i - 1] = hi;
    bv[i] = lo;
  }
}

// Register scatter by runtime slot via cndmask chain (stays in VGPRs: all
// array indices are unroll literals — rule #20).
__device__ __forceinline__ void rec10(int (&a)[KK], int cnt, int j) {
#pragma unroll
  for (int r = 0; r < KK; ++r) a[r] = (cnt == r) ? j : a[r];
}
__device__ __forceinline__ void rec8(int (&a)[TCAP], int cnt, int j) {
#pragma unroll
  for (int r = 0; r < TCAP; ++r) a[r] = (cnt == r) ? j : a[r];
}

// ---------------------------------------------------------------------------
// Kernel A1: per-chunk top-10 neg-dist VALUES (no indices).
// Grid (16*CHUNKS, BB, NT) = 1792 blocks -> ~7 waves/SIMD occupancy.
// ---------------------------------------------------------------------------
__global__ __launch_bounds__(256) void knn_thr_partial(
    const float* __restrict__ pts4, float* __restrict__ part) {
  __shared__ float4 cand[CSZ];  // 16 KB
  const int qg = blockIdx.x >> 2;      // query group 0..15
  const int c = blockIdx.x & 3;        // chunk 0..3
  const int b = blockIdx.y, t = blockIdx.z;
  const float4* src0 = (const float4*)pts4 + ((size_t)(b * TT + t) * PP);
  const int jbase = c * CSZ;

  for (int i = threadIdx.x; i < CSZ; i += 256) {
    float4 v = src0[jbase + i];
    v.w = fmaf(v.x, v.x, fmaf(v.y, v.y, v.z * v.z));
    cand[i] = v;
  }
  __syncthreads();

  const int p = qg * 256 + threadIdx.x;
  float4 q = src0[p];
  q.w = fmaf(q.x, q.x, fmaf(q.y, q.y, q.z * q.z));

  float bv[KK];
#pragma unroll
  for (int i = 0; i < KK; ++i) bv[i] = -INFINITY;

  for (int j = 0; j < CSZ; j += 4) {
    float4 c0 = cand[j], c1 = cand[j + 1], c2 = cand[j + 2], c3 = cand[j + 3];
    float nd0 = neg_dist(q, c0);
    float nd1 = neg_dist(q, c1);
    float nd2 = neg_dist(q, c2);
    float nd3 = neg_dist(q, c3);
    ins_val(bv, nd0);
    ins_val(bv, nd1);
    ins_val(bv, nd2);
    ins_val(bv, nd3);
  }

  const size_t qid = (size_t)(t * BB + b) * PP + p;
#pragma unroll
  for (int r = 0; r < KK; ++r)
    part[(size_t)(c * KK + r) * NQ + qid] = bv[r];
}

// ---------------------------------------------------------------------------
// Kernel B: merge partial values -> exact 10th-largest thr, then full rescan.
// Hot loop is LOAD-FREE in the branch bodies: indices recorded into registers
// (strict '>' set + '==' ties in ascending order); all src1 gathers + disp_var
// math deferred to a once-per-thread epilogue. Set semantics identical to
// jax.lax.top_k (strict winners + first (10-cnt) ties by ascending index).
// ---------------------------------------------------------------------------
__global__ __launch_bounds__(256) void knn_collect(
    const float* __restrict__ pts4, const float* __restrict__ part,
    int* __restrict__ idx_out, float* __restrict__ dv_out) {
  __shared__ float4 cand[PP];  // 64 KB
  const int qg = blockIdx.x;
  const int b = blockIdx.y, t = blockIdx.z;
  const float4* src0 = (const float4*)pts4 + ((size_t)(b * TT + t) * PP);
  const float4* src1 = src0 + PP;  // frame t+1

  for (int i = threadIdx.x; i < PP; i += 256) {
    float4 v = src0[i];
    v.w = fmaf(v.x, v.x, fmaf(v.y, v.y, v.z * v.z));
    cand[i] = v;
  }
  __syncthreads();

  const int p = qg * 256 + threadIdx.x;
  const size_t g = (size_t)(t * BB + b) * PP + p;

  // ---- exact 10th-largest value over all 4096 (tournament of chunk top-10s)
  float bv[KK];
#pragma unroll
  for (int i = 0; i < KK; ++i) bv[i] = -INFINITY;
#pragma unroll
  for (int c = 0; c < CHUNKS; ++c) {
#pragma unroll
    for (int r = 0; r < KK; ++r) ins_val(bv, part[(size_t)(c * KK + r) * NQ + g]);
  }
  const float thr = bv[KK - 1];

  const float4 q = cand[p];  // has xx in .w

  int cnt = 0, tcnt = 0;
  int fsel[KK], tsel[TCAP];
#pragma unroll
  for (int r = 0; r < KK; ++r) fsel[r] = 0;
#pragma unroll
  for (int r = 0; r < TCAP; ++r) tsel[r] = 0;

  // 8-wide flat: 8 LDS reads issue up front (in flight across the branchy
  // tail since branch bodies touch no memory).
  for (int j = 0; j < PP; j += 8) {
    float4 c0 = cand[j], c1 = cand[j + 1], c2 = cand[j + 2], c3 = cand[j + 3];
    float4 c4 = cand[j + 4], c5 = cand[j + 5], c6 = cand[j + 6], c7 = cand[j + 7];
    float nd0 = neg_dist(q, c0), nd1 = neg_dist(q, c1);
    float nd2 = neg_dist(q, c2), nd3 = neg_dist(q, c3);
    float nd4 = neg_dist(q, c4), nd5 = neg_dist(q, c5);
    float nd6 = neg_dist(q, c6), nd7 = neg_dist(q, c7);
#define REC(nd, jj)                                   \
    if ((nd) >= thr) {                                \
      if ((nd) > thr) { rec10(fsel, cnt, (jj)); ++cnt; } \
      else { rec8(tsel, tcnt, (jj)); ++tcnt; }        \
    }
    REC(nd0, j); REC(nd1, j + 1); REC(nd2, j + 2); REC(nd3, j + 3);
    REC(nd4, j + 4); REC(nd5, j + 5); REC(nd6, j + 6); REC(nd7, j + 7);
#undef REC
  }

  // ---- epilogue: gathers + disp_var, once per thread
  float4 a1 = src1[p];
  const float dqx = a1.x - q.x, dqy = a1.y - q.y, dqz = a1.z - q.z;
  float s = 0.0f;
  int* myidx = idx_out + g * KK;

#pragma unroll
  for (int r = 0; r < KK; ++r) {
    if (r < cnt) {
      int j = fsel[r];
      float4 cc = cand[j];
      float4 n1 = src1[j];
      float dx = (n1.x - cc.x) - dqx;
      float dy = (n1.y - cc.y) - dqy;
      float dz = (n1.z - cc.z) - dqz;
      s += fmaf(dx, dx, fmaf(dy, dy, dz * dz));
      myidx[r] = j;
    }
  }
  const int need = KK - cnt;  // >= 1
#pragma unroll
  for (int r = 0; r < TCAP; ++r) {
    if (r < need) {
      int j = tsel[r];
      float4 cc = cand[j];
      float4 n1 = src1[j];
      float dx = (n1.x - cc.x) - dqx;
      float dy = (n1.y - cc.y) - dqy;
      float dz = (n1.z - cc.z) - dqz;
      s += fmaf(dx, dx, fmaf(dy, dy, dz * dz));
      myidx[cnt + r] = j;
    }
  }

  dv_out[g] = s * (1.0f / KK);
}

// ---------------------------------------------------------------------------
// Kernel B2: transpose encoded[b][d][t*P+p] -> featT[t][b][p][d]  (t < NT)
// ---------------------------------------------------------------------------
__global__ __launch_bounds__(256) void transpose_kernel(
    const float* __restrict__ encoded, float* __restrict__ featT) {
  __shared__ float tile[32][33];
  const int slice = blockIdx.z;  // t*BB + b
  const int t = slice / BB, b = slice % BB;
  const int p0 = blockIdx.x * 32, d0 = blockIdx.y * 32;
  const int tx = threadIdx.x, ty = threadIdx.y;
#pragma unroll
  for (int r = 0; r < 4; ++r) {
    int d = d0 + ty + r * 8;
    tile[ty + r * 8][tx] =
        encoded[((size_t)(b * DD + d)) * (TT * PP) + (size_t)t * PP + p0 + tx];
  }
  __syncthreads();
#pragma unroll
  for (int r = 0; r < 4; ++r) {
    int p = p0 + ty + r * 8;
    featT[((size_t)slice * PP + p) * DD + d0 + tx] = tile[tx][ty + r * 8];
  }
}

// ---------------------------------------------------------------------------
// Kernel N: per-point feature L2 norms (wave per point)
// ---------------------------------------------------------------------------
__global__ __launch_bounds__(256) void norms_kernel(
    const float* __restrict__ featT, float* __restrict__ norms) {
  const int w = threadIdx.x >> 6, lane = threadIdx.x & 63;
  const int wid = blockIdx.x * 4 + w;
  for (int i = 0; i < 32; ++i) {
    const int g = wid * 32 + i;
    float2 f = *(const float2*)(featT + (size_t)g * DD + lane * 2);
    float part = fmaf(f.x, f.x, f.y * f.y);
#pragma unroll
    for (int o = 32; o > 0; o >>= 1) part += __shfl_xor(part, o);
    if (lane == 0) norms[g] = sqrtf(part);
  }
}

// ---------------------------------------------------------------------------
// Kernel C: exact lower-median per t via 4-pass radix select on float bits
// ---------------------------------------------------------------------------
__global__ __launch_bounds__(256) void median_kernel(
    const float* __restrict__ disp_var, float* __restrict__ scale) {
  const int t = blockIdx.x;
  const unsigned* u = (const unsigned*)(disp_var + (size_t)t * BP);
  __shared__ unsigned hist[256];
  __shared__ unsigned sh_prefix;
  __shared__ int sh_rank;
  if (threadIdx.x == 0) { sh_prefix = 0u; sh_rank = (BP - 1) >> 1; }
  __syncthreads();
  for (int pass = 0; pass < 4; ++pass) {
    const int shift = 24 - pass * 8;
    hist[threadIdx.x] = 0u;
    __syncthreads();
    const unsigned hmask = (pass == 0) ? 0u : (0xFFFFFFFFu << (shift + 8));
    const unsigned prefix = sh_prefix;
    for (int i = threadIdx.x; i < BP; i += 256) {
      unsigned v = u[i];
      if ((v & hmask) == prefix) atomicAdd(&hist[(v >> shift) & 255u], 1u);
    }
    __syncthreads();
    if (threadIdx.x == 0) {
      int rank = sh_rank;
      unsigned run = 0u;
      for (int c = 0; c < 256; ++c) {
        unsigned h = hist[c];
        if (run + h > (unsigned)rank) {
          sh_rank = rank - (int)run;
          sh_prefix = prefix | ((unsigned)c << shift);
          break;
        }
        run += h;
      }
    }
    __syncthreads();
  }
  if (threadIdx.x == 0) {
    float med = __uint_as_float(sh_prefix);
    scale[t] = fmaxf(med, 1e-6f);
  }
}

// ---------------------------------------------------------------------------
// Kernel D: cosine similarity + rigidity loss, deterministic block partials
// ---------------------------------------------------------------------------
__global__ __launch_bounds__(256) void cos_loss_kernel(
    const float* __restrict__ featT, const int* __restrict__ idxw,
    const float* __restrict__ norms, const float* __restrict__ dv,
    const float* __restrict__ scale, float* __restrict__ partial) {
  const int w = threadIdx.x >> 6, lane = threadIdx.x & 63;
  __shared__ float wsum[4];
  float acc = 0.0f;
  const int qbase = blockIdx.x * QPB + w * (QPB / 4);
  for (int i = 0; i < QPB / 4; ++i) {
    const int g = qbase + i;
    const int t = g >> 14;
    const int p = g & (PP - 1);
    const int slice = g - p;        // base of this (t,b) slice
    const float* fbase = featT + (size_t)g * DD;
    float2 fq = *(const float2*)(fbase + lane * 2);
    float nq = fmaxf(norms[g], 1e-8f);
    const int* ip = idxw + (size_t)g * KK;
    float msum = 0.0f;
#pragma unroll
    for (int k = 0; k < KK; ++k) {
      int j = ip[k];
      const float* nb = featT + (size_t)(slice + j) * DD;
      float2 fn = *(const float2*)(nb + lane * 2);
      float part = fmaf(fq.x, fn.x, fq.y * fn.y);
#pragma unroll
      for (int o = 32; o > 0; o >>= 1) part += __shfl_xor(part, o);
      float nn = fmaxf(norms[slice + j], 1e-8f);
      msum += part / (nq * nn);
    }
    float mean_sim = msum * (1.0f / KK);
    float rig = expf(-dv[g] / scale[t]);
    acc += rig * (1.0f - mean_sim);
  }
  if (lane == 0) wsum[w] = acc;
  __syncthreads();
  if (threadIdx.x == 0)
    partial[blockIdx.x] = (wsum[0] + wsum[1]) + (wsum[2] + wsum[3]);
}

// ---------------------------------------------------------------------------
// Kernel E: final deterministic reduce -> scalar loss
// ---------------------------------------------------------------------------
__global__ __launch_bounds__(256) void final_reduce_kernel(
    const float* __restrict__ partial, float* __restrict__ out) {
  __shared__ float sh[256];
  float s = 0.0f;
  for (int i = threadIdx.x; i < NBLK_COS; i += 256) s += partial[i];
  sh[threadIdx.x] = s;
  __syncthreads();
  for (int st = 128; st > 0; st >>= 1) {
    if (threadIdx.x < st) sh[threadIdx.x] += sh[threadIdx.x + st];
    __syncthreads();
  }
  if (threadIdx.x == 0) out[0] = sh[0] * (1.0f / (float)NQ);
}

extern "C" void kernel_launch(void* const* d_in, const int* in_sizes, int n_in,
                              void* d_out, int out_size, void* d_ws,
                              size_t ws_size, hipStream_t stream) {
  const float* encoded = (const float*)d_in[0];
  const float* pts4 = (const float*)d_in[1];
  char* ws = (char*)d_ws;
  float* featT = (float*)(ws + OFF_FEATT);
  float* part = (float*)(ws + OFF_FEATT);  // aliases featT (consumed first)
  int* idxw = (int*)(ws + OFF_IDX);
  float* dv = (float*)(ws + OFF_DV);
  float* norms = (float*)(ws + OFF_NORM);
  float* scale = (float*)(ws + OFF_SCALE);
  float* partial = (float*)(ws + OFF_PART);
  float* outp = (float*)d_out;

  knn_thr_partial<<<dim3(16 * CHUNKS, BB, NT), 256, 0, stream>>>(pts4, part);
  knn_collect<<<dim3(16, BB, NT), 256, 0, stream>>>(pts4, part, idxw, dv);
  transpose_kernel<<<dim3(PP / 32, DD / 32, NT * BB), dim3(32, 8), 0, stream>>>(
      encoded, featT);
  norms_kernel<<<NBLK_COS, 256, 0, stream>>>(featT, norms);
  median_kernel<<<NT, 256, 0, stream>>>(dv, scale);
  cos_loss_kernel<<<NBLK_COS, 256, 0, stream>>>(featT, idxw, norms, dv, scale,
                                                partial);
  final_reduce_kernel<<<1, 256, 0, stream>>>(partial, outp);
}